// Round 4
// baseline (190.141 us; speedup 1.0000x reference)
//
#include <hip/hip_runtime.h>
#include <hip/hip_bf16.h>

// Problem: x (16,256,32,32) fp32, weight (8193,256) fp32 (emb = first 8192 rows).
// Rows: r = b*1024 + (h*32+w), xf[r][c] = x[b*262144 + c*1024 + (r&1023)].
// Outputs (flat fp32): xq (4194304) | loss (1) | code-as-float (16384).
//
// R4: (1) prep_e wave-reduce instead of 64-way-colliding LDS atomicAdd;
// (2) top-2 per 128-code tile packed into ONE u64 (two u32 = score-bits|idx7),
//     8.4 MB in d_ws -> no d_out aliasing; (3) fuse prep_x+prep_e and
//     refine+gather+loss (last-block finalize). 4 launches total.

#define N_ROWS   16384
#define KCODES   8192
#define DIM      256
#define LOSS_OFF 4194304
#define CODE_OFF 4194305
#define MARGIN_ACC 0.006f          // covers f16 noise (~8e-4 rms) + 4.9e-4 idx-mask quant

typedef _Float16 half8  __attribute__((ext_vector_type(8)));
typedef _Float16 half4v __attribute__((ext_vector_type(4)));
typedef float    float4v __attribute__((ext_vector_type(4)));
typedef unsigned long long u64;

__device__ __forceinline__ unsigned umax32(unsigned a, unsigned b) { return a > b ? a : b; }
__device__ __forceinline__ unsigned umin32(unsigned a, unsigned b) { return a < b ? a : b; }
__device__ __forceinline__ void gll16(const _Float16* g, _Float16* l) {
  __builtin_amdgcn_global_load_lds((const __attribute__((address_space(1))) void*)g,
                                   (__attribute__((address_space(3))) void*)l, 16, 0, 0);
}

// Swizzled tile layout (xh and eh): per 128-row tile, per 64-half K-chunk,
// 16B unit u = row_local*8 + (kgrp ^ (row_local & 7)); chunk = 8192 halves.

// ---------------------------------------------------------------- fused prep
__global__ __launch_bounds__(256) void k_prep(const float* __restrict__ x, _Float16* __restrict__ xh,
                                              const float* __restrict__ wt, _Float16* __restrict__ eh,
                                              float* __restrict__ en2c) {
  __shared__ __align__(16) _Float16 ls[8192];   // e-path only: 32 codes x 256 halves
  __shared__ float es[32];
  int t = threadIdx.x;
  if (blockIdx.x < 256) {
    // ---- x path: 256 blocks x 64 rows
    int blk = blockIdx.x;
    int row = t & 63;
    int s   = t >> 6;                // 0..3
    int r   = blk * 64 + row;
    int b   = r >> 10;
    int n   = r & 1023;
    const float* xb = x + (size_t)b * 262144 + n;
    int r7 = r & 7, rl = r & 127;
    size_t tb = (size_t)(r >> 7) * 32768;
    for (int j = 0; j < 8; ++j) {
      int g = s + 4 * j;             // c-group 0..31 (8 halves each)
      int chunk = g >> 3, kg = g & 7;
      half8 h;
#pragma unroll
      for (int i = 0; i < 8; ++i) h[i] = (_Float16)xb[(size_t)(g * 8 + i) * 1024];
      int p = kg ^ r7;
      *(half8*)&xh[tb + (size_t)chunk * 8192 + rl * 64 + p * 8] = h;
    }
  } else {
    // ---- e path: 256 blocks x 32 codes
    int blk  = blockIdx.x - 256;
    int lane = t & 63, wv = t >> 6;
    int k0 = blk * 32;
    const float* wb = wt + (size_t)k0 * 256;
    for (int i = 0; i < 8; ++i) {
      int lin = i * 1024 + t * 4;                 // all lanes of a wave share lin>>8 = i*4+wv
      float4v v = *(const float4v*)&wb[lin];
      half4v h; float ss = 0.f;
#pragma unroll
      for (int j = 0; j < 4; ++j) { h[j] = (_Float16)v[j]; ss = fmaf(v[j], v[j], ss); }
      *(half4v*)&ls[lin] = h;
#pragma unroll
      for (int d = 32; d; d >>= 1) ss += __shfl_xor(ss, d);
      if (lane == 0) es[i * 4 + wv] = ss;
    }
    __syncthreads();
    size_t tb = (size_t)(k0 >> 7) * 32768;
    for (int i = 0; i < 4; ++i) {
      int u = i * 256 + t;
      int code_l = u >> 5;
      int cu = u & 31, chunk = cu >> 3, p = cu & 7;
      int kgl = k0 + code_l;
      int kg = p ^ (kgl & 7);
      half8 h = *(half8*)&ls[code_l * 256 + chunk * 64 + kg * 8];
      *(half8*)&eh[tb + (size_t)chunk * 8192 + (size_t)(kgl & 127) * 64 + p * 8] = h;
    }
    if (t < 32) en2c[k0 + t] = 32.0f - 0.5f * es[t];
  }
}

// ---------------------------------------------------------------- main GEMM (A=codes, B=xrows) + top-2 epilogue
__global__ __launch_bounds__(256) void k_gemm(const _Float16* __restrict__ xh, const _Float16* __restrict__ eh,
                                              const float* __restrict__ en2c,
                                              u64* __restrict__ top2) {
  __shared__ __align__(16) _Float16 As[8192];   // 128 codes x 64 halves (swizzled)
  __shared__ __align__(16) _Float16 Bs[8192];   // 128 xrows x 64 halves (swizzled)
  int t    = threadIdx.x;
  int bx   = blockIdx.x;   // code tile 0..63 (128 codes)
  int by   = blockIdx.y;   // xrow tile 0..127 (128 rows)
  int lane = t & 63, w = t >> 6;
  int wr = w & 1, wc = w >> 1;                  // wave: codes 64*wr, xrows 64*wc
  int ln15 = lane & 15, q = lane >> 4;
  int q4 = q * 4;

  const _Float16* Ag = eh + (size_t)bx * 32768;
  const _Float16* Bg = xh + (size_t)by * 32768;

  int kwave = bx * 128 + wr * 64;
  float4v cin[4];
#pragma unroll
  for (int mi = 0; mi < 4; ++mi) cin[mi] = *(const float4v*)&en2c[kwave + mi * 16 + q4];

  float4v acc[4][4];
#pragma unroll
  for (int mi = 0; mi < 4; ++mi)
#pragma unroll
    for (int ni = 0; ni < 4; ++ni) acc[mi][ni] = cin[mi];

  int so = (w * 64 + lane) * 8;                 // staging source offset (halves)
  int lo = w * 512;                             // per-wave LDS dest offset (halves)

  for (int ch = 0; ch < 4; ++ch) {
    if (ch) __syncthreads();
    const _Float16* ac = Ag + ch * 8192;
    const _Float16* bc = Bg + ch * 8192;
#pragma unroll
    for (int i = 0; i < 4; ++i) {
      gll16(ac + i * 2048 + so, As + i * 2048 + lo);
      gll16(bc + i * 2048 + so, Bs + i * 2048 + lo);
    }
    __syncthreads();
#pragma unroll
    for (int ks = 0; ks < 2; ++ks) {
      half8 af[4], bf[4];
#pragma unroll
      for (int mi = 0; mi < 4; ++mi) {
        int row = wr * 64 + mi * 16 + ln15;     // code row
        af[mi] = *(const half8*)&As[(row * 8 + ((ks * 4 + q) ^ (row & 7))) * 8];
      }
#pragma unroll
      for (int ni = 0; ni < 4; ++ni) {
        int row = wc * 64 + ni * 16 + ln15;     // xrow
        bf[ni] = *(const half8*)&Bs[(row * 8 + ((ks * 4 + q) ^ (row & 7))) * 8];
      }
#pragma unroll
      for (int mi = 0; mi < 4; ++mi)
#pragma unroll
        for (int ni = 0; ni < 4; ++ni)
          acc[mi][ni] = __builtin_amdgcn_mfma_f32_16x16x32_f16(af[mi], bf[ni], acc[mi][ni], 0, 0, 0);
    }
  }

  // epilogue: per x-row top-2 (max of biased acc) over this wave's 64 codes.
  // pack = (score bits & ~0x7F) | (7-bit block-local code index).
  __syncthreads();                              // frag reads done; reuse As
  u64* ep = (u64*)(void*)As;                    // [128 xrows][2 wr]
  int ibase = wr * 64 + q4;

#pragma unroll
  for (int ni = 0; ni < 4; ++ni) {
    unsigned hi[8], lo2[8];
#pragma unroll
    for (int j = 0; j < 8; ++j) {
      int mi = j >> 1, rb = (j & 1) * 2;
      unsigned p0 = (__float_as_uint(acc[mi][ni][rb])     & 0xFFFFFF80u) | (unsigned)(ibase + mi * 16 + rb);
      unsigned p1 = (__float_as_uint(acc[mi][ni][rb + 1]) & 0xFFFFFF80u) | (unsigned)(ibase + mi * 16 + rb + 1);
      hi[j] = umax32(p0, p1); lo2[j] = umin32(p0, p1);
    }
#pragma unroll
    for (int st = 4; st; st >>= 1)
#pragma unroll
      for (int j = 0; j < 8; ++j) if (j < st) {
        unsigned nb = umax32(hi[j], hi[j + st]);
        unsigned ns = umax32(umin32(hi[j], hi[j + st]), umax32(lo2[j], lo2[j + st]));
        hi[j] = nb; lo2[j] = ns;
      }
    unsigned b = hi[0], s = lo2[0];
#pragma unroll
    for (int d = 16; d < 64; d <<= 1) {
      unsigned ob = __shfl_xor(b, d);
      unsigned os = __shfl_xor(s, d);
      unsigned ns = umax32(umin32(b, ob), umax32(s, os));
      b = umax32(b, ob); s = ns;
    }
    if (q == 0) {
      int rl = wc * 64 + ni * 16 + ln15;
      ep[rl * 2 + wr] = ((u64)b << 32) | s;
    }
  }
  __syncthreads();
  if (t < 128) {
    u64 A = ep[t * 2 + 0], B = ep[t * 2 + 1];
    unsigned a0 = (unsigned)(A >> 32), a1 = (unsigned)A;
    unsigned b0 = (unsigned)(B >> 32), b1 = (unsigned)B;
    unsigned best = umax32(a0, b0);
    unsigned sec  = umax32(umin32(a0, b0), umax32(a1, b1));
    top2[((size_t)by * 128 + t) * 64 + bx] = ((u64)best << 32) | sec;
  }
}

// ---------------------------------------------------------------- fused refine + gather + loss
__global__ __launch_bounds__(256) void k_refine_out(const u64* __restrict__ top2,
                                                    const float* __restrict__ x, const float* __restrict__ w,
                                                    float* __restrict__ out,
                                                    float* __restrict__ lacc, unsigned* __restrict__ cnt) {
  __shared__ float ec[32 * 261];
  __shared__ int   cds[32];
  __shared__ float part[4];
  int t    = threadIdx.x;
  int lane = t & 63, wv = t >> 6;
  int blk  = blockIdx.x;               // 512 blocks x 32 rows
  int row0 = blk * 32;
  int b = row0 >> 10, n0 = row0 & 1023;

  // ---- phase 1: refine codes for this block's 32 rows (wave wv: rows wv+4j)
  for (int j = 0; j < 8; ++j) {
    int rl  = wv + 4 * j;
    int row = row0 + rl;
    u64 e = top2[(size_t)row * 64 + lane];       // lane = code-tile index
    unsigned hi = (unsigned)(e >> 32), lo = (unsigned)e;
    unsigned mx = hi;
#pragma unroll
    for (int d = 1; d < 64; d <<= 1) mx = umax32(mx, __shfl_xor(mx, d));
    float fm = __uint_as_float(mx & 0xFFFFFF80u);
    float th = fm - MARGIN_ACC;
    bool c0 = __uint_as_float(hi & 0xFFFFFF80u) >= th;
    bool c1 = __uint_as_float(lo & 0xFFFFFF80u) >= th;
    u64 bal0 = __ballot(c0), bal1 = __ballot(c1);
    int kbest;
    if (__popcll(bal0) + __popcll(bal1) <= 1) {
      int l0 = __ffsll((unsigned long long)__ballot(hi == mx)) - 1;
      kbest = l0 * 128 + (int)(__shfl(hi, l0) & 127u);
    } else {
      int n = row & 1023;
      const float* xr = x + (size_t)b * 262144 + n;
      float4v ex;
#pragma unroll
      for (int i = 0; i < 4; ++i) ex[i] = xr[(size_t)(lane * 4 + i) * 1024];
      double bs = 1e300; int bk = 0x7fffffff;
      for (int pass = 0; pass < 2; ++pass) {
        u64 bal = pass ? bal1 : bal0;
        unsigned src = pass ? lo : hi;
        while (bal) {
          int l = __ffsll((unsigned long long)bal) - 1;
          bal &= bal - 1;
          int kc = l * 128 + (int)(__shfl(src, l) & 127u);
          float4v wv4 = *(const float4v*)&w[(size_t)kc * DIM + lane * 4];
          double s = 0.0;
#pragma unroll
          for (int i = 0; i < 4; ++i) { double ev = (double)wv4[i]; s += ev * (ev - 2.0 * (double)ex[i]); }
#pragma unroll
          for (int d = 1; d < 64; d <<= 1) s += __shfl_xor(s, d);
          if (s < bs || (s == bs && kc < bk)) { bs = s; bk = kc; }
        }
      }
      kbest = bk;
    }
    if (lane == 0) { cds[rl] = kbest; out[CODE_OFF + row] = (float)kbest; }
  }
  __syncthreads();

  // ---- phase 2: gather e-rows to LDS, write xq, accumulate loss
  {
    int rr = t >> 6;
    int c4 = (t & 63) * 4;
    for (int j = 0; j < 8; ++j) {
      int r = rr + 4 * j;
      float4v v = *(const float4v*)&w[(size_t)cds[r] * DIM + c4];
#pragma unroll
      for (int i = 0; i < 4; ++i) ec[r * 261 + c4 + i] = v[i];
    }
  }
  __syncthreads();
  float ls = 0.f;
  int r2 = t & 31;
  int cg = t >> 5;
  const size_t base = (size_t)b * 262144 + n0 + r2;
  for (int j = 0; j < 32; ++j) {
    int c = cg * 32 + j;
    float v  = ec[r2 * 261 + c];
    size_t a = base + (size_t)c * 1024;
    float xv = x[a];
    out[a] = v;
    float d = v - xv;
    ls = fmaf(d, d, ls);
  }
#pragma unroll
  for (int d = 32; d; d >>= 1) ls += __shfl_xor(ls, d);
  if (lane == 0) part[wv] = ls;
  __syncthreads();
  if (t == 0) {
    atomicAdd(lacc, part[0] + part[1] + part[2] + part[3]);
    __threadfence();
    unsigned old = atomicAdd(cnt, 1u);
    if (old == 511u) {
      __threadfence();
      out[LOSS_OFF] = 1.25f * (*(volatile float*)lacc) / 4194304.0f;
    }
  }
}

// ---------------------------------------------------------------- launch
extern "C" void kernel_launch(void* const* d_in, const int* in_sizes, int n_in,
                              void* d_out, int out_size, void* d_ws, size_t ws_size,
                              hipStream_t stream) {
  const float* x = (const float*)d_in[0];
  const float* w = (const float*)d_in[1];
  float* out = (float*)d_out;
  char* ws = (char*)d_ws;
  _Float16* xh   = (_Float16*)(ws);                 //  8,388,608 B
  _Float16* eh   = (_Float16*)(ws + 8388608);       //  4,194,304 B
  float*    en2c = (float*)(ws + 12582912);         //     32,768 B
  u64*      top2 = (u64*)(ws + 12615680);           //  8,388,608 B (16384 rows x 64 u64)
  float*    lacc = (float*)(ws + 21004288);         //          4 B
  unsigned* cnt  = (unsigned*)(ws + 21004292);      //          4 B

  hipMemsetAsync(lacc, 0, 8, stream);
  k_prep<<<512, 256, 0, stream>>>(x, xh, w, eh, en2c);
  k_gemm<<<dim3(64, 128), 256, 0, stream>>>(xh, eh, en2c, top2);
  k_refine_out<<<512, 256, 0, stream>>>(top2, x, w, out, lacc, cnt);
}

// Round 5
// 180.250 us; speedup vs baseline: 1.0549x; 1.0549x over previous
//
#include <hip/hip_runtime.h>
#include <hip/hip_bf16.h>

// Problem: x (16,256,32,32) fp32, weight (8193,256) fp32 (emb = first 8192 rows).
// Rows: r = b*1024 + (h*32+w), xf[r][c] = x[b*262144 + c*1024 + (r&1023)].
// Outputs (flat fp32): xq (4194304) | loss (1) | code-as-float (16384).
//
// R5: helpers rebuilt for full-wave (256B+) transactions:
//  - k_prep x-path: float4 loads + LDS transpose + contiguous swizzled stores;
//    block 0 zeroes lacc/cnt (no memset dispatch).
//  - k_refine standalone, 4096 blocks (1 row/wave) — R3 parallelism, R4 format.
//  - k_out: 64-row blocks, 256B x/xq transactions, XOR-swizzled 64KB LDS,
//    per-thread code register, last-block loss finalize.
// k_gemm unchanged (m97-plateau, ~88 us, MfmaUtil ~34%).

#define N_ROWS   16384
#define KCODES   8192
#define DIM      256
#define LOSS_OFF 4194304
#define CODE_OFF 4194305
#define MARGIN_ACC 0.006f          // covers f16 noise (~8e-4 rms) + 4.9e-4 idx-mask quant

typedef _Float16 half8  __attribute__((ext_vector_type(8)));
typedef _Float16 half4v __attribute__((ext_vector_type(4)));
typedef float    float4v __attribute__((ext_vector_type(4)));
typedef unsigned long long u64;

__device__ __forceinline__ unsigned umax32(unsigned a, unsigned b) { return a > b ? a : b; }
__device__ __forceinline__ unsigned umin32(unsigned a, unsigned b) { return a < b ? a : b; }
__device__ __forceinline__ void gll16(const _Float16* g, _Float16* l) {
  __builtin_amdgcn_global_load_lds((const __attribute__((address_space(1))) void*)g,
                                   (__attribute__((address_space(3))) void*)l, 16, 0, 0);
}

// Swizzled tile layout (xh and eh): per 128-row tile, per 64-half K-chunk,
// 16B unit u = row_local*8 + (kgrp ^ (row_local & 7)); chunk = 8192 halves.

// ---------------------------------------------------------------- fused prep
__global__ __launch_bounds__(256) void k_prep(const float* __restrict__ x, _Float16* __restrict__ xh,
                                              const float* __restrict__ wt, _Float16* __restrict__ eh,
                                              float* __restrict__ en2c,
                                              float* __restrict__ lacc, unsigned* __restrict__ cnt) {
  __shared__ __align__(16) _Float16 ls[8192];
  __shared__ float es[32];
  int t = threadIdx.x;
  if (blockIdx.x < 256) {
    // ---- x path: 256 blocks x 64 rows. LDS transpose, then swizzled stores.
    if (blockIdx.x == 0 && t == 0) { *lacc = 0.f; *cnt = 0u; }
    int blk  = blockIdx.x;
    int row0 = blk * 64;
    int b    = row0 >> 10;
    int n0   = row0 & 1023;
    const float* xb = x + (size_t)b * 262144 + n0;   // view: xb[c*1024 + n_local]
    _Float16 (*lsx)[72] = (_Float16(*)[72])ls;       // [64 n][72 c-stride]
    int c_l = t >> 2;                                // 0..63
    int ng0 = t & 3;                                 // 0..3
    for (int cc = 0; cc < 4; ++cc) {                 // 64-c chunk = xh K-chunk
      if (cc) __syncthreads();
#pragma unroll
      for (int p = 0; p < 4; ++p) {
        int ng = ng0 + 4 * p;                        // 0..15
        float4v v = *(const float4v*)&xb[(size_t)(cc * 64 + c_l) * 1024 + ng * 4];
#pragma unroll
        for (int k = 0; k < 4; ++k) lsx[ng * 4 + k][c_l] = (_Float16)v[k];
      }
      __syncthreads();
#pragma unroll
      for (int p2 = 0; p2 < 2; ++p2) {
        int unit = t + 256 * p2;                     // 0..511 = 64 rows x 8 units
        int rl64 = unit >> 3, p7 = unit & 7;
        int r = row0 + rl64;
        int kg = p7 ^ (r & 7);
        half8 h = *(const half8*)&lsx[rl64][kg * 8];
        size_t tb = (size_t)(r >> 7) * 32768;
        *(half8*)&xh[tb + (size_t)cc * 8192 + (size_t)(r & 127) * 64 + p7 * 8] = h;
      }
    }
  } else {
    // ---- e path: 256 blocks x 32 codes
    int blk  = blockIdx.x - 256;
    int lane = t & 63, wv = t >> 6;
    int k0 = blk * 32;
    const float* wb = wt + (size_t)k0 * 256;
    for (int i = 0; i < 8; ++i) {
      int lin = i * 1024 + t * 4;                 // all lanes of a wave share lin>>8 = i*4+wv
      float4v v = *(const float4v*)&wb[lin];
      half4v h; float ss = 0.f;
#pragma unroll
      for (int j = 0; j < 4; ++j) { h[j] = (_Float16)v[j]; ss = fmaf(v[j], v[j], ss); }
      *(half4v*)&ls[lin] = h;
#pragma unroll
      for (int d = 32; d; d >>= 1) ss += __shfl_xor(ss, d);
      if (lane == 0) es[i * 4 + wv] = ss;
    }
    __syncthreads();
    size_t tb = (size_t)(k0 >> 7) * 32768;
    for (int i = 0; i < 4; ++i) {
      int u = i * 256 + t;
      int code_l = u >> 5;
      int cu = u & 31, chunk = cu >> 3, p = cu & 7;
      int kgl = k0 + code_l;
      int kg = p ^ (kgl & 7);
      half8 h = *(half8*)&ls[code_l * 256 + chunk * 64 + kg * 8];
      *(half8*)&eh[tb + (size_t)chunk * 8192 + (size_t)(kgl & 127) * 64 + p * 8] = h;
    }
    if (t < 32) en2c[k0 + t] = 32.0f - 0.5f * es[t];
  }
}

// ---------------------------------------------------------------- main GEMM (A=codes, B=xrows) + top-2 epilogue
__global__ __launch_bounds__(256) void k_gemm(const _Float16* __restrict__ xh, const _Float16* __restrict__ eh,
                                              const float* __restrict__ en2c,
                                              u64* __restrict__ top2) {
  __shared__ __align__(16) _Float16 As[8192];   // 128 codes x 64 halves (swizzled)
  __shared__ __align__(16) _Float16 Bs[8192];   // 128 xrows x 64 halves (swizzled)
  int t    = threadIdx.x;
  int bx   = blockIdx.x;   // code tile 0..63 (128 codes)
  int by   = blockIdx.y;   // xrow tile 0..127 (128 rows)
  int lane = t & 63, w = t >> 6;
  int wr = w & 1, wc = w >> 1;                  // wave: codes 64*wr, xrows 64*wc
  int ln15 = lane & 15, q = lane >> 4;
  int q4 = q * 4;

  const _Float16* Ag = eh + (size_t)bx * 32768;
  const _Float16* Bg = xh + (size_t)by * 32768;

  int kwave = bx * 128 + wr * 64;
  float4v cin[4];
#pragma unroll
  for (int mi = 0; mi < 4; ++mi) cin[mi] = *(const float4v*)&en2c[kwave + mi * 16 + q4];

  float4v acc[4][4];
#pragma unroll
  for (int mi = 0; mi < 4; ++mi)
#pragma unroll
    for (int ni = 0; ni < 4; ++ni) acc[mi][ni] = cin[mi];

  int so = (w * 64 + lane) * 8;                 // staging source offset (halves)
  int lo = w * 512;                             // per-wave LDS dest offset (halves)

  for (int ch = 0; ch < 4; ++ch) {
    if (ch) __syncthreads();
    const _Float16* ac = Ag + ch * 8192;
    const _Float16* bc = Bg + ch * 8192;
#pragma unroll
    for (int i = 0; i < 4; ++i) {
      gll16(ac + i * 2048 + so, As + i * 2048 + lo);
      gll16(bc + i * 2048 + so, Bs + i * 2048 + lo);
    }
    __syncthreads();
#pragma unroll
    for (int ks = 0; ks < 2; ++ks) {
      half8 af[4], bf[4];
#pragma unroll
      for (int mi = 0; mi < 4; ++mi) {
        int row = wr * 64 + mi * 16 + ln15;     // code row
        af[mi] = *(const half8*)&As[(row * 8 + ((ks * 4 + q) ^ (row & 7))) * 8];
      }
#pragma unroll
      for (int ni = 0; ni < 4; ++ni) {
        int row = wc * 64 + ni * 16 + ln15;     // xrow
        bf[ni] = *(const half8*)&Bs[(row * 8 + ((ks * 4 + q) ^ (row & 7))) * 8];
      }
#pragma unroll
      for (int mi = 0; mi < 4; ++mi)
#pragma unroll
        for (int ni = 0; ni < 4; ++ni)
          acc[mi][ni] = __builtin_amdgcn_mfma_f32_16x16x32_f16(af[mi], bf[ni], acc[mi][ni], 0, 0, 0);
    }
  }

  // epilogue: per x-row top-2 (max of biased acc) over this wave's 64 codes.
  // pack = (score bits & ~0x7F) | (7-bit block-local code index).
  __syncthreads();                              // frag reads done; reuse As
  u64* ep = (u64*)(void*)As;                    // [128 xrows][2 wr]
  int ibase = wr * 64 + q4;

#pragma unroll
  for (int ni = 0; ni < 4; ++ni) {
    unsigned hi[8], lo2[8];
#pragma unroll
    for (int j = 0; j < 8; ++j) {
      int mi = j >> 1, rb = (j & 1) * 2;
      unsigned p0 = (__float_as_uint(acc[mi][ni][rb])     & 0xFFFFFF80u) | (unsigned)(ibase + mi * 16 + rb);
      unsigned p1 = (__float_as_uint(acc[mi][ni][rb + 1]) & 0xFFFFFF80u) | (unsigned)(ibase + mi * 16 + rb + 1);
      hi[j] = umax32(p0, p1); lo2[j] = umin32(p0, p1);
    }
#pragma unroll
    for (int st = 4; st; st >>= 1)
#pragma unroll
      for (int j = 0; j < 8; ++j) if (j < st) {
        unsigned nb = umax32(hi[j], hi[j + st]);
        unsigned ns = umax32(umin32(hi[j], hi[j + st]), umax32(lo2[j], lo2[j + st]));
        hi[j] = nb; lo2[j] = ns;
      }
    unsigned b = hi[0], s = lo2[0];
#pragma unroll
    for (int d = 16; d < 64; d <<= 1) {
      unsigned ob = __shfl_xor(b, d);
      unsigned os = __shfl_xor(s, d);
      unsigned ns = umax32(umin32(b, ob), umax32(s, os));
      b = umax32(b, ob); s = ns;
    }
    if (q == 0) {
      int rl = wc * 64 + ni * 16 + ln15;
      ep[rl * 2 + wr] = ((u64)b << 32) | s;
    }
  }
  __syncthreads();
  if (t < 128) {
    u64 A = ep[t * 2 + 0], B = ep[t * 2 + 1];
    unsigned a0 = (unsigned)(A >> 32), a1 = (unsigned)A;
    unsigned b0 = (unsigned)(B >> 32), b1 = (unsigned)B;
    unsigned best = umax32(a0, b0);
    unsigned sec  = umax32(umin32(a0, b0), umax32(a1, b1));
    top2[((size_t)by * 128 + t) * 64 + bx] = ((u64)best << 32) | sec;
  }
}

// ---------------------------------------------------------------- refine: exact fp64 argmin over candidates
__global__ __launch_bounds__(256) void k_refine(const u64* __restrict__ top2,
                                                const float* __restrict__ x, const float* __restrict__ w,
                                                int* __restrict__ code, float* __restrict__ out) {
  int t = threadIdx.x, lane = t & 63, wv = t >> 6;
  int row = blockIdx.x * 4 + wv;
  u64 e = top2[(size_t)row * 64 + lane];        // lane = code-tile index
  unsigned hi = (unsigned)(e >> 32), lo = (unsigned)e;
  unsigned mx = hi;
#pragma unroll
  for (int d = 1; d < 64; d <<= 1) mx = umax32(mx, __shfl_xor(mx, d));
  float fm = __uint_as_float(mx & 0xFFFFFF80u);
  float th = fm - MARGIN_ACC;
  bool c0 = __uint_as_float(hi & 0xFFFFFF80u) >= th;
  bool c1 = __uint_as_float(lo & 0xFFFFFF80u) >= th;
  u64 bal0 = __ballot(c0), bal1 = __ballot(c1);
  int kbest;
  if (__popcll(bal0) + __popcll(bal1) <= 1) {
    int l0 = __ffsll((unsigned long long)__ballot(hi == mx)) - 1;
    kbest = l0 * 128 + (int)(__shfl(hi, l0) & 127u);
  } else {
    int b = row >> 10, n = row & 1023;
    const float* xr = x + (size_t)b * 262144 + n;
    float4v ex;
#pragma unroll
    for (int i = 0; i < 4; ++i) ex[i] = xr[(size_t)(lane * 4 + i) * 1024];
    double bs = 1e300; int bk = 0x7fffffff;
    for (int pass = 0; pass < 2; ++pass) {
      u64 bal = pass ? bal1 : bal0;
      unsigned src = pass ? lo : hi;
      while (bal) {
        int l = __ffsll((unsigned long long)bal) - 1;
        bal &= bal - 1;
        int kc = l * 128 + (int)(__shfl(src, l) & 127u);
        float4v wv4 = *(const float4v*)&w[(size_t)kc * DIM + lane * 4];
        double s = 0.0;
#pragma unroll
        for (int i = 0; i < 4; ++i) { double ev = (double)wv4[i]; s += ev * (ev - 2.0 * (double)ex[i]); }
#pragma unroll
        for (int d = 1; d < 64; d <<= 1) s += __shfl_xor(s, d);
        if (s < bs || (s == bs && kc < bk)) { bs = s; bk = kc; }
      }
    }
    kbest = bk;
  }
  if (lane == 0) { code[row] = kbest; out[CODE_OFF + row] = (float)kbest; }
}

// ---------------------------------------------------------------- gather xq + loss (64-row blocks, full-wave txns)
__global__ __launch_bounds__(256) void k_out(const int* __restrict__ code, const float* __restrict__ w,
                                             const float* __restrict__ x, float* __restrict__ out,
                                             float* __restrict__ lacc, unsigned* __restrict__ cnt) {
  __shared__ float ec[64 * 256];       // [r][c ^ (r&31)] XOR-swizzled: col reads & gather writes 2-way
  int t    = threadIdx.x;
  int lane = t & 63, wv = t >> 6;
  int blk  = blockIdx.x;               // 256 blocks x 64 rows
  int row0 = blk * 64;
  int b = row0 >> 10, n0 = row0 & 1023;

  int kc = code[row0 + lane];          // this thread's row (r = lane) code
  const float* wr = w + (size_t)kc * 256;
  int sw = lane & 31;
#pragma unroll 4
  for (int i = 0; i < 16; ++i) {
    int c4 = (wv * 16 + i) * 4;        // c group
    float4v v = *(const float4v*)&wr[c4];
#pragma unroll
    for (int k = 0; k < 4; ++k) ec[lane * 256 + ((c4 + k) ^ sw)] = v[k];
  }
  __syncthreads();

  float ls = 0.f;
  const size_t base = (size_t)b * 262144 + n0 + lane;
  for (int j = 0; j < 64; ++j) {
    int c = wv * 64 + j;
    float v = ec[lane * 256 + (c ^ sw)];
    size_t a = base + (size_t)c * 1024;
    float xv = x[a];
    out[a] = v;
    float d = v - xv;
    ls = fmaf(d, d, ls);
  }
#pragma unroll
  for (int d = 32; d; d >>= 1) ls += __shfl_xor(ls, d);
  __syncthreads();                     // ec reads done; reuse slot 0..3
  if (lane == 0) ec[wv] = ls;
  __syncthreads();
  if (t == 0) {
    atomicAdd(lacc, ec[0] + ec[1] + ec[2] + ec[3]);
    __threadfence();
    unsigned old = atomicAdd(cnt, 1u);
    if (old == 255u) {
      __threadfence();
      out[LOSS_OFF] = 1.25f * (*(volatile float*)lacc) / 4194304.0f;
    }
  }
}

// ---------------------------------------------------------------- launch
extern "C" void kernel_launch(void* const* d_in, const int* in_sizes, int n_in,
                              void* d_out, int out_size, void* d_ws, size_t ws_size,
                              hipStream_t stream) {
  const float* x = (const float*)d_in[0];
  const float* w = (const float*)d_in[1];
  float* out = (float*)d_out;
  char* ws = (char*)d_ws;
  _Float16* xh   = (_Float16*)(ws);                 //  8,388,608 B
  _Float16* eh   = (_Float16*)(ws + 8388608);       //  4,194,304 B
  float*    en2c = (float*)(ws + 12582912);         //     32,768 B
  u64*      top2 = (u64*)(ws + 12615680);           //  8,388,608 B (16384 rows x 64 u64)
  int*      codep = (int*)(ws + 21004288);          //     65,536 B
  float*    lacc = (float*)(ws + 21069824);         //          4 B
  unsigned* cnt  = (unsigned*)(ws + 21069828);      //          4 B

  k_prep<<<512, 256, 0, stream>>>(x, xh, w, eh, en2c, lacc, cnt);
  k_gemm<<<dim3(64, 128), 256, 0, stream>>>(xh, eh, en2c, top2);
  k_refine<<<4096, 256, 0, stream>>>(top2, x, w, codep, out);
  k_out<<<256, 256, 0, stream>>>(codep, w, x, out, lacc, cnt);
}

// Round 6
// 178.137 us; speedup vs baseline: 1.0674x; 1.0119x over previous
//
#include <hip/hip_runtime.h>
#include <hip/hip_bf16.h>

// Problem: x (16,256,32,32) fp32, weight (8193,256) fp32 (emb = first 8192 rows).
// Rows: r = b*1024 + (h*32+w), xf[r][c] = x[b*262144 + c*1024 + (r&1023)].
// Outputs (flat fp32): xq (4194304) | loss (1) | code-as-float (16384).
//
// R6: (1) top2 layout transposed to [bx][row] -> k_gemm epilogue stores are
// contiguous 1KB/block (was 4x write-amplified cross-XCD 8B/line partials);
// (2) k_refine fused into k_out (all lanes know kbest -> inline gather),
// 512 threads/block, transposed stride-65 LDS (conflict-free both phases).
// 3 launches.

#define N_ROWS   16384
#define KCODES   8192
#define DIM      256
#define LOSS_OFF 4194304
#define CODE_OFF 4194305
#define MARGIN_ACC 0.006f          // covers f16 noise (~8e-4 rms) + 4.9e-4 idx-mask quant

typedef _Float16 half8  __attribute__((ext_vector_type(8)));
typedef _Float16 half4v __attribute__((ext_vector_type(4)));
typedef float    float4v __attribute__((ext_vector_type(4)));
typedef unsigned long long u64;

__device__ __forceinline__ unsigned umax32(unsigned a, unsigned b) { return a > b ? a : b; }
__device__ __forceinline__ unsigned umin32(unsigned a, unsigned b) { return a < b ? a : b; }
__device__ __forceinline__ void gll16(const _Float16* g, _Float16* l) {
  __builtin_amdgcn_global_load_lds((const __attribute__((address_space(1))) void*)g,
                                   (__attribute__((address_space(3))) void*)l, 16, 0, 0);
}

// Swizzled tile layout (xh and eh): per 128-row tile, per 64-half K-chunk,
// 16B unit u = row_local*8 + (kgrp ^ (row_local & 7)); chunk = 8192 halves.

// ---------------------------------------------------------------- fused prep
__global__ __launch_bounds__(256) void k_prep(const float* __restrict__ x, _Float16* __restrict__ xh,
                                              const float* __restrict__ wt, _Float16* __restrict__ eh,
                                              float* __restrict__ en2c,
                                              float* __restrict__ lacc, unsigned* __restrict__ cnt) {
  __shared__ __align__(16) _Float16 ls[8192];
  __shared__ float es[32];
  int t = threadIdx.x;
  if (blockIdx.x < 256) {
    // ---- x path: 256 blocks x 64 rows. LDS transpose, then swizzled stores.
    if (blockIdx.x == 0 && t == 0) { *lacc = 0.f; *cnt = 0u; }
    int blk  = blockIdx.x;
    int row0 = blk * 64;
    int b    = row0 >> 10;
    int n0   = row0 & 1023;
    const float* xb = x + (size_t)b * 262144 + n0;   // view: xb[c*1024 + n_local]
    _Float16 (*lsx)[72] = (_Float16(*)[72])ls;       // [64 n][72 c-stride]
    int c_l = t >> 2;                                // 0..63
    int ng0 = t & 3;                                 // 0..3
    for (int cc = 0; cc < 4; ++cc) {                 // 64-c chunk = xh K-chunk
      if (cc) __syncthreads();
#pragma unroll
      for (int p = 0; p < 4; ++p) {
        int ng = ng0 + 4 * p;                        // 0..15
        float4v v = *(const float4v*)&xb[(size_t)(cc * 64 + c_l) * 1024 + ng * 4];
#pragma unroll
        for (int k = 0; k < 4; ++k) lsx[ng * 4 + k][c_l] = (_Float16)v[k];
      }
      __syncthreads();
#pragma unroll
      for (int p2 = 0; p2 < 2; ++p2) {
        int unit = t + 256 * p2;                     // 0..511 = 64 rows x 8 units
        int rl64 = unit >> 3, p7 = unit & 7;
        int r = row0 + rl64;
        int kg = p7 ^ (r & 7);
        half8 h = *(const half8*)&lsx[rl64][kg * 8];
        size_t tb = (size_t)(r >> 7) * 32768;
        *(half8*)&xh[tb + (size_t)cc * 8192 + (size_t)(r & 127) * 64 + p7 * 8] = h;
      }
    }
  } else {
    // ---- e path: 256 blocks x 32 codes
    int blk  = blockIdx.x - 256;
    int lane = t & 63, wv = t >> 6;
    int k0 = blk * 32;
    const float* wb = wt + (size_t)k0 * 256;
    for (int i = 0; i < 8; ++i) {
      int lin = i * 1024 + t * 4;                 // all lanes of a wave share lin>>8 = i*4+wv
      float4v v = *(const float4v*)&wb[lin];
      half4v h; float ss = 0.f;
#pragma unroll
      for (int j = 0; j < 4; ++j) { h[j] = (_Float16)v[j]; ss = fmaf(v[j], v[j], ss); }
      *(half4v*)&ls[lin] = h;
#pragma unroll
      for (int d = 32; d; d >>= 1) ss += __shfl_xor(ss, d);
      if (lane == 0) es[i * 4 + wv] = ss;
    }
    __syncthreads();
    size_t tb = (size_t)(k0 >> 7) * 32768;
    for (int i = 0; i < 4; ++i) {
      int u = i * 256 + t;
      int code_l = u >> 5;
      int cu = u & 31, chunk = cu >> 3, p = cu & 7;
      int kgl = k0 + code_l;
      int kg = p ^ (kgl & 7);
      half8 h = *(half8*)&ls[code_l * 256 + chunk * 64 + kg * 8];
      *(half8*)&eh[tb + (size_t)chunk * 8192 + (size_t)(kgl & 127) * 64 + p * 8] = h;
    }
    if (t < 32) en2c[k0 + t] = 32.0f - 0.5f * es[t];
  }
}

// ---------------------------------------------------------------- main GEMM (A=codes, B=xrows) + top-2 epilogue
__global__ __launch_bounds__(256) void k_gemm(const _Float16* __restrict__ xh, const _Float16* __restrict__ eh,
                                              const float* __restrict__ en2c,
                                              u64* __restrict__ top2) {
  __shared__ __align__(16) _Float16 As[8192];   // 128 codes x 64 halves (swizzled)
  __shared__ __align__(16) _Float16 Bs[8192];   // 128 xrows x 64 halves (swizzled)
  int t    = threadIdx.x;
  int bx   = blockIdx.x;   // code tile 0..63 (128 codes)
  int by   = blockIdx.y;   // xrow tile 0..127 (128 rows)
  int lane = t & 63, w = t >> 6;
  int wr = w & 1, wc = w >> 1;                  // wave: codes 64*wr, xrows 64*wc
  int ln15 = lane & 15, q = lane >> 4;
  int q4 = q * 4;

  const _Float16* Ag = eh + (size_t)bx * 32768;
  const _Float16* Bg = xh + (size_t)by * 32768;

  int kwave = bx * 128 + wr * 64;
  float4v cin[4];
#pragma unroll
  for (int mi = 0; mi < 4; ++mi) cin[mi] = *(const float4v*)&en2c[kwave + mi * 16 + q4];

  float4v acc[4][4];
#pragma unroll
  for (int mi = 0; mi < 4; ++mi)
#pragma unroll
    for (int ni = 0; ni < 4; ++ni) acc[mi][ni] = cin[mi];

  int so = (w * 64 + lane) * 8;                 // staging source offset (halves)
  int lo = w * 512;                             // per-wave LDS dest offset (halves)

  for (int ch = 0; ch < 4; ++ch) {
    if (ch) __syncthreads();
    const _Float16* ac = Ag + ch * 8192;
    const _Float16* bc = Bg + ch * 8192;
#pragma unroll
    for (int i = 0; i < 4; ++i) {
      gll16(ac + i * 2048 + so, As + i * 2048 + lo);
      gll16(bc + i * 2048 + so, Bs + i * 2048 + lo);
    }
    __syncthreads();
#pragma unroll
    for (int ks = 0; ks < 2; ++ks) {
      half8 af[4], bf[4];
#pragma unroll
      for (int mi = 0; mi < 4; ++mi) {
        int row = wr * 64 + mi * 16 + ln15;     // code row
        af[mi] = *(const half8*)&As[(row * 8 + ((ks * 4 + q) ^ (row & 7))) * 8];
      }
#pragma unroll
      for (int ni = 0; ni < 4; ++ni) {
        int row = wc * 64 + ni * 16 + ln15;     // xrow
        bf[ni] = *(const half8*)&Bs[(row * 8 + ((ks * 4 + q) ^ (row & 7))) * 8];
      }
#pragma unroll
      for (int mi = 0; mi < 4; ++mi)
#pragma unroll
        for (int ni = 0; ni < 4; ++ni)
          acc[mi][ni] = __builtin_amdgcn_mfma_f32_16x16x32_f16(af[mi], bf[ni], acc[mi][ni], 0, 0, 0);
    }
  }

  // epilogue: per x-row top-2 (max of biased acc) over this wave's 64 codes.
  // pack = (score bits & ~0x7F) | (7-bit block-local code index).
  __syncthreads();                              // frag reads done; reuse As
  u64* ep = (u64*)(void*)As;                    // [128 xrows][2 wr]
  int ibase = wr * 64 + q4;

#pragma unroll
  for (int ni = 0; ni < 4; ++ni) {
    unsigned hi[8], lo2[8];
#pragma unroll
    for (int j = 0; j < 8; ++j) {
      int mi = j >> 1, rb = (j & 1) * 2;
      unsigned p0 = (__float_as_uint(acc[mi][ni][rb])     & 0xFFFFFF80u) | (unsigned)(ibase + mi * 16 + rb);
      unsigned p1 = (__float_as_uint(acc[mi][ni][rb + 1]) & 0xFFFFFF80u) | (unsigned)(ibase + mi * 16 + rb + 1);
      hi[j] = umax32(p0, p1); lo2[j] = umin32(p0, p1);
    }
#pragma unroll
    for (int st = 4; st; st >>= 1)
#pragma unroll
      for (int j = 0; j < 8; ++j) if (j < st) {
        unsigned nb = umax32(hi[j], hi[j + st]);
        unsigned ns = umax32(umin32(hi[j], hi[j + st]), umax32(lo2[j], lo2[j + st]));
        hi[j] = nb; lo2[j] = ns;
      }
    unsigned b = hi[0], s = lo2[0];
#pragma unroll
    for (int d = 16; d < 64; d <<= 1) {
      unsigned ob = __shfl_xor(b, d);
      unsigned os = __shfl_xor(s, d);
      unsigned ns = umax32(umin32(b, ob), umax32(s, os));
      b = umax32(b, ob); s = ns;
    }
    if (q == 0) {
      int rl = wc * 64 + ni * 16 + ln15;
      ep[rl * 2 + wr] = ((u64)b << 32) | s;
    }
  }
  __syncthreads();
  if (t < 128) {
    u64 A = ep[t * 2 + 0], B = ep[t * 2 + 1];
    unsigned a0 = (unsigned)(A >> 32), a1 = (unsigned)A;
    unsigned b0 = (unsigned)(B >> 32), b1 = (unsigned)B;
    unsigned best = umax32(a0, b0);
    unsigned sec  = umax32(umin32(a0, b0), umax32(a1, b1));
    // transposed layout [bx][row]: contiguous 1KB per block, no cross-XCD
    // partial-line write sharing.
    top2[(size_t)bx * 16384 + (size_t)by * 128 + t] = ((u64)best << 32) | sec;
  }
}

// ---------------------------------------------------------------- fused refine + gather + loss
__global__ __launch_bounds__(512) void k_out(const u64* __restrict__ top2,
                                             const float* __restrict__ x, const float* __restrict__ w,
                                             float* __restrict__ out,
                                             float* __restrict__ lacc, unsigned* __restrict__ cnt) {
  __shared__ float ect[256 * 65];      // [c][r] transposed, stride 65: phase1 stores
                                       // bank=(lane+r)%32, phase2 reads bank=lane%32 — both <=2-way
  __shared__ float part[8];
  int t    = threadIdx.x;
  int lane = t & 63, wv = t >> 6;
  int blk  = blockIdx.x;               // 256 blocks x 64 rows
  int row0 = blk * 64;
  int b = row0 >> 10, n0 = row0 & 1023;

  // ---- phase 0+1: refine + inline gather, 8 rows per wave
  for (int j = 0; j < 8; ++j) {
    int rl  = wv * 8 + j;
    int row = row0 + rl;
    u64 e = top2[(size_t)lane * 16384 + row];    // lane = code-tile index (8 rows/line -> L1 reuse)
    unsigned hi = (unsigned)(e >> 32), lo = (unsigned)e;
    unsigned mx = hi;
#pragma unroll
    for (int d = 1; d < 64; d <<= 1) mx = umax32(mx, __shfl_xor(mx, d));
    float fm = __uint_as_float(mx & 0xFFFFFF80u);
    float th = fm - MARGIN_ACC;
    bool c0 = __uint_as_float(hi & 0xFFFFFF80u) >= th;
    bool c1 = __uint_as_float(lo & 0xFFFFFF80u) >= th;
    u64 bal0 = __ballot(c0), bal1 = __ballot(c1);
    int kbest;
    if (__popcll(bal0) + __popcll(bal1) <= 1) {
      int l0 = __ffsll((unsigned long long)__ballot(hi == mx)) - 1;
      kbest = l0 * 128 + (int)(__shfl(hi, l0) & 127u);
    } else {
      const float* xr = x + (size_t)b * 262144 + (row & 1023);
      float4v ex;
#pragma unroll
      for (int i = 0; i < 4; ++i) ex[i] = xr[(size_t)(lane * 4 + i) * 1024];
      double bs = 1e300; int bk = 0x7fffffff;
      for (int pass = 0; pass < 2; ++pass) {
        u64 bal = pass ? bal1 : bal0;
        unsigned src = pass ? lo : hi;
        while (bal) {
          int l = __ffsll((unsigned long long)bal) - 1;
          bal &= bal - 1;
          int kc = l * 128 + (int)(__shfl(src, l) & 127u);
          float4v wv4 = *(const float4v*)&w[(size_t)kc * DIM + lane * 4];
          double s = 0.0;
#pragma unroll
          for (int i = 0; i < 4; ++i) { double ev = (double)wv4[i]; s += ev * (ev - 2.0 * (double)ex[i]); }
#pragma unroll
          for (int d = 1; d < 64; d <<= 1) s += __shfl_xor(s, d);
          if (s < bs || (s == bs && kc < bk)) { bs = s; bk = kc; }
        }
      }
      kbest = bk;                                // all lanes agree (shuffle-reduced)
    }
    if (lane == 0) out[CODE_OFF + row] = (float)kbest;
    // inline gather: whole wave loads this row's e-vector (coalesced 256B x4)
    const float* wrow = w + (size_t)kbest * 256;
#pragma unroll
    for (int i = 0; i < 4; ++i) ect[(i * 64 + lane) * 65 + rl] = wrow[i * 64 + lane];
  }
  __syncthreads();

  // ---- phase 2: write xq (full-wave 256B txns), accumulate loss
  float ls = 0.f;
  const size_t base = (size_t)b * 262144 + n0 + lane;
  for (int j = 0; j < 32; ++j) {
    int c = wv * 32 + j;
    float v = ect[c * 65 + lane];
    size_t a = base + (size_t)c * 1024;
    float xv = x[a];
    out[a] = v;
    float d = v - xv;
    ls = fmaf(d, d, ls);
  }
#pragma unroll
  for (int d = 32; d; d >>= 1) ls += __shfl_xor(ls, d);
  if (lane == 0) part[wv] = ls;
  __syncthreads();
  if (t == 0) {
    float s = part[0] + part[1] + part[2] + part[3] + part[4] + part[5] + part[6] + part[7];
    atomicAdd(lacc, s);
    __threadfence();
    unsigned old = atomicAdd(cnt, 1u);
    if (old == 255u) {
      __threadfence();
      out[LOSS_OFF] = 1.25f * (*(volatile float*)lacc) / 4194304.0f;
    }
  }
}

// ---------------------------------------------------------------- launch
extern "C" void kernel_launch(void* const* d_in, const int* in_sizes, int n_in,
                              void* d_out, int out_size, void* d_ws, size_t ws_size,
                              hipStream_t stream) {
  const float* x = (const float*)d_in[0];
  const float* w = (const float*)d_in[1];
  float* out = (float*)d_out;
  char* ws = (char*)d_ws;
  _Float16* xh   = (_Float16*)(ws);                 //  8,388,608 B
  _Float16* eh   = (_Float16*)(ws + 8388608);       //  4,194,304 B
  float*    en2c = (float*)(ws + 12582912);         //     32,768 B
  u64*      top2 = (u64*)(ws + 12615680);           //  8,388,608 B ([64 bx][16384 row] u64)
  float*    lacc = (float*)(ws + 21004288);         //          4 B
  unsigned* cnt  = (unsigned*)(ws + 21004292);      //          4 B

  k_prep<<<512, 256, 0, stream>>>(x, xh, w, eh, en2c, lacc, cnt);
  k_gemm<<<dim3(64, 128), 256, 0, stream>>>(xh, eh, en2c, top2);
  k_out<<<256, 512, 0, stream>>>(top2, x, w, out, lacc, cnt);
}